// Round 2
// baseline (127.882 us; speedup 1.0000x reference)
//
#include <hip/hip_runtime.h>

#define PATCH 7
#define HALO 3
#define BLOCK_X 256
#define OUT_COLS (BLOCK_X - 2 * HALO) /* 250 */
#define TILE_H 64
#define EPS 0.002f

// Per-channel 7x7 clipped box stats -> alpha/beta.
// Vertical sliding-window sums per thread-column; horizontal 7-sum via LDS.
__global__ __launch_bounds__(BLOCK_X) void ProgressiveTransfer_kernel(
    const float* __restrict__ G, const float* __restrict__ S,
    float* __restrict__ out, int H, int W)
{
    const int t  = threadIdx.x;
    const int ch = blockIdx.z;
    const int x  = blockIdx.x * OUT_COLS + t - HALO;  // this thread's column
    const int y0 = blockIdx.y * TILE_H;
    const int y1 = min(y0 + TILE_H, H);

    const size_t plane = (size_t)H * W;
    const float* Gp = G + (size_t)ch * plane;
    const float* Sp = S + (size_t)ch * plane;

    const bool xin = (x >= 0 && x < W);

    __shared__ float ls_g1[BLOCK_X];
    __shared__ float ls_g2[BLOCK_X];
    __shared__ float ls_s1[BLOCK_X];
    __shared__ float ls_s2[BLOCK_X];

    // Vertical window sums over rows [y-3, y+3] of g, g^2, s, s^2 (zero-padded).
    float vg1 = 0.f, vg2 = 0.f, vs1 = 0.f, vs2 = 0.f;

    // Init with rows [y0-3, y0+2]; first loop iteration adds row y0+3.
    for (int r = y0 - HALO; r < y0 + HALO; ++r) {
        float g = 0.f, s = 0.f;
        if (xin && r >= 0 && r < H) {
            g = Gp[(size_t)r * W + x];
            s = Sp[(size_t)r * W + x];
        }
        vg1 += g; vg2 += g * g;
        vs1 += s; vs2 += s * s;
    }

    for (int y = y0; y < y1; ++y) {
        // Slide window: add row y+3; drop row y-4 only if it was added
        // (init started at y0-3, so nothing to drop on the first iteration).
        {
            const int rn = y + HALO;
            float g = 0.f, s = 0.f;
            if (xin && rn < H) {
                g = Gp[(size_t)rn * W + x];
                s = Sp[(size_t)rn * W + x];
            }
            vg1 += g; vg2 += g * g;
            vs1 += s; vs2 += s * s;
            const int ro = y - HALO - 1;
            if (xin && y > y0 && ro >= 0) {
                const float go = Gp[(size_t)ro * W + x];
                const float so = Sp[(size_t)ro * W + x];
                vg1 -= go; vg2 -= go * go;
                vs1 -= so; vs2 -= so * so;
            }
        }

        ls_g1[t] = vg1; ls_g2[t] = vg2;
        ls_s1[t] = vs1; ls_s2[t] = vs2;
        __syncthreads();

        if (t >= HALO && t < BLOCK_X - HALO && x < W) {
            float hg1 = 0.f, hg2 = 0.f, hs1 = 0.f, hs2 = 0.f;
#pragma unroll
            for (int k = -HALO; k <= HALO; ++k) {
                hg1 += ls_g1[t + k];
                hg2 += ls_g2[t + k];
                hs1 += ls_s1[t + k];
                hs2 += ls_s2[t + k];
            }
            const float cntx = (float)(min(x + HALO, W - 1) - max(x - HALO, 0) + 1);
            const float cnty = (float)(min(y + HALO, H - 1) - max(y - HALO, 0) + 1);
            const float cnt  = cntx * cnty;
            const float inv  = 1.0f / cnt;
            const float invm = 1.0f / (cnt - 1.0f);
            const float mg = hg1 * inv;
            const float ms = hs1 * inv;
            const float varg = (hg2 - hg1 * mg) * invm;
            const float vars = (hs2 - hs1 * ms) * invm;
            const float stdg = sqrtf(fmaxf(varg, 0.0f));
            const float stds = sqrtf(fmaxf(vars, 0.0f));
            const float alpha = stdg / (stds + EPS);
            const float beta  = mg - alpha * ms;

            const size_t base = ((size_t)ch * H + y) * W + x;
            out[base] = alpha;                 // out[0][ch][y][x]
            out[3 * plane + base] = beta;      // out[1][ch][y][x]
        }
        __syncthreads();
    }
}

extern "C" void kernel_launch(void* const* d_in, const int* in_sizes, int n_in,
                              void* d_out, int out_size, void* d_ws, size_t ws_size,
                              hipStream_t stream) {
    (void)n_in; (void)d_ws; (void)ws_size; (void)in_sizes; (void)out_size;
    const float* guidance = (const float*)d_in[0];
    const float* source   = (const float*)d_in[1];
    float* out = (float*)d_out;

    const int C = 3, H = 2048, W = 3072;

    dim3 block(BLOCK_X, 1, 1);
    dim3 grid((W + OUT_COLS - 1) / OUT_COLS, (H + TILE_H - 1) / TILE_H, C);
    ProgressiveTransfer_kernel<<<grid, block, 0, stream>>>(guidance, source, out, H, W);
}

// Round 3
// 88.681 us; speedup vs baseline: 1.4420x; 1.4420x over previous
//
#include <hip/hip_runtime.h>

#define HALO 3
#define TILE_H 32
#define STRIP_OUT 240   /* output columns per wave; input strip = 256 cols */
#define EPS 0.002f

__device__ __forceinline__ float rcp_fast(float x) { return __builtin_amdgcn_rcpf(x); }

// One wave (64 lanes) per strip; each lane owns 4 consecutive columns.
// Vertical 7-window sliding sums in registers; horizontal 7-sum via shuffles.
// No LDS, no barriers.
__global__ __launch_bounds__(64) void ProgressiveTransfer_kernel(
    const float* __restrict__ G, const float* __restrict__ S,
    float* __restrict__ out, int H, int W)
{
    const int t  = threadIdx.x;                       // lane 0..63
    const int ch = blockIdx.z;
    const int y0 = blockIdx.y * TILE_H;
    const int col0 = blockIdx.x * STRIP_OUT - 8 + 4 * t;  // lane's first column
    const bool cin = (col0 >= 0) && (col0 + 3 < W);   // vectors are all-in or all-out

    const size_t plane = (size_t)H * W;
    const float* Gp = G + (size_t)ch * plane;
    const float* Sp = S + (size_t)ch * plane;

    // Vertical window sums over rows [y-3, y+3] for the lane's 4 columns.
    float g1[4] = {0,0,0,0}, g2[4] = {0,0,0,0};
    float s1[4] = {0,0,0,0}, s2[4] = {0,0,0,0};

    auto row_add = [&](int r) {
        if (!cin || r < 0 || r >= H) return;
        const float4 g = *reinterpret_cast<const float4*>(Gp + (size_t)r * W + col0);
        const float4 s = *reinterpret_cast<const float4*>(Sp + (size_t)r * W + col0);
        g1[0] += g.x; g2[0] += g.x * g.x; s1[0] += s.x; s2[0] += s.x * s.x;
        g1[1] += g.y; g2[1] += g.y * g.y; s1[1] += s.y; s2[1] += s.y * s.y;
        g1[2] += g.z; g2[2] += g.z * g.z; s1[2] += s.z; s2[2] += s.z * s.z;
        g1[3] += g.w; g2[3] += g.w * g.w; s1[3] += s.w; s2[3] += s.w * s.w;
    };
    auto row_sub = [&](int r) {
        if (!cin || r < 0) return;
        const float4 g = *reinterpret_cast<const float4*>(Gp + (size_t)r * W + col0);
        const float4 s = *reinterpret_cast<const float4*>(Sp + (size_t)r * W + col0);
        g1[0] -= g.x; g2[0] -= g.x * g.x; s1[0] -= s.x; s2[0] -= s.x * s.x;
        g1[1] -= g.y; g2[1] -= g.y * g.y; s1[1] -= s.y; s2[1] -= s.y * s.y;
        g1[2] -= g.z; g2[2] -= g.z * g.z; s1[2] -= s.z; s2[2] -= s.z * s.z;
        g1[3] -= g.w; g2[3] -= g.w * g.w; s1[3] -= s.w; s2[3] -= s.w * s.w;
    };

    // 7-wide horizontal sums centered at each of the lane's 4 columns.
    // Window spans only lanes t-1, t, t+1 (halo 3 < 4 cols/lane).
    auto hsum = [&](const float* c, float* o) {
        const float S4   = c[0] + c[1] + c[2] + c[3];
        const float sfx1 = c[3];
        const float sfx2 = c[2] + c[3];
        const float sfx3 = c[1] + sfx2;
        const float pfx1 = c[0];
        const float pfx2 = c[0] + c[1];
        const float pfx3 = pfx2 + c[2];
        const float S1m = __shfl_up(sfx1, 1);
        const float S2m = __shfl_up(sfx2, 1);
        const float S3m = __shfl_up(sfx3, 1);
        const float P1p = __shfl_down(pfx1, 1);
        const float P2p = __shfl_down(pfx2, 1);
        const float P3p = __shfl_down(pfx3, 1);
        o[0] = S3m + S4;              // cols [c0-3, c0+3]
        o[1] = S2m + S4 + P1p;        // cols [c1-3, c1+3]
        o[2] = S1m + S4 + P2p;
        o[3] = S4 + P3p;
    };

    // Per-column horizontal clipped counts (loop-invariant).
    float cntx[4];
#pragma unroll
    for (int j = 0; j < 4; ++j) {
        const int x = col0 + j;
        cntx[j] = (float)(min(x + HALO, W - 1) - max(x - HALO, 0) + 1);
    }

    const bool wout = (t >= 2) && (t < 62) && (col0 < W);

    // Init vertical sums with rows [y0-3, y0+2]; loop adds y+3.
    for (int r = y0 - HALO; r < y0 + HALO; ++r) row_add(r);

    const int y1 = min(y0 + TILE_H, H);
    for (int y = y0; y < y1; ++y) {
        row_add(y + HALO);
        if (y > y0) row_sub(y - HALO - 1);

        float hg1[4], hg2[4], hs1[4], hs2[4];
        hsum(g1, hg1); hsum(g2, hg2); hsum(s1, hs1); hsum(s2, hs2);

        const float cnty = (float)(min(y + HALO, H - 1) - max(y - HALO, 0) + 1);

        float4 av, bv;
        float* ap = &av.x;
        float* bp = &bv.x;
#pragma unroll
        for (int j = 0; j < 4; ++j) {
            const float cnt  = cntx[j] * cnty;
            const float inv  = rcp_fast(cnt);
            const float invm = rcp_fast(cnt - 1.0f);
            const float mg = hg1[j] * inv;
            const float ms = hs1[j] * inv;
            const float varg = (hg2[j] - hg1[j] * mg) * invm;
            const float vars = (hs2[j] - hs1[j] * ms) * invm;
            const float stdg = __builtin_amdgcn_sqrtf(fmaxf(varg, 0.0f));
            const float stds = __builtin_amdgcn_sqrtf(fmaxf(vars, 0.0f));
            const float alpha = stdg * rcp_fast(stds + EPS);
            ap[j] = alpha;
            bp[j] = mg - alpha * ms;
        }

        if (wout) {
            const size_t base = (size_t)ch * plane + (size_t)y * W + col0;
            *reinterpret_cast<float4*>(out + base) = av;                // alpha
            *reinterpret_cast<float4*>(out + 3 * plane + base) = bv;    // beta
        }
    }
}

extern "C" void kernel_launch(void* const* d_in, const int* in_sizes, int n_in,
                              void* d_out, int out_size, void* d_ws, size_t ws_size,
                              hipStream_t stream) {
    (void)n_in; (void)d_ws; (void)ws_size; (void)in_sizes; (void)out_size;
    const float* guidance = (const float*)d_in[0];
    const float* source   = (const float*)d_in[1];
    float* out = (float*)d_out;

    const int C = 3, H = 2048, W = 3072;
    const int nstrips = (W + STRIP_OUT - 1) / STRIP_OUT;   // 13

    dim3 block(64, 1, 1);
    dim3 grid(nstrips, H / TILE_H, C);
    ProgressiveTransfer_kernel<<<grid, block, 0, stream>>>(guidance, source, out, H, W);
}